// Round 10
// baseline (225.971 us; speedup 1.0000x reference)
//
#include <hip/hip_runtime.h>
#include <hip/hip_bf16.h>

typedef unsigned short u16;
typedef __bf16 bf8v __attribute__((ext_vector_type(8)));
typedef float f4v __attribute__((ext_vector_type(4)));

__device__ __forceinline__ float b2f(u16 v) {
  union { unsigned u; float f; } x; x.u = ((unsigned)v) << 16; return x.f;
}
__device__ __forceinline__ u16 f2b(float f) {
  union { float f; unsigned u; } x; x.f = f;
  unsigned r = (x.u + 0x7FFFu + ((x.u >> 16) & 1u)) >> 16;
  return (u16)r;
}
__device__ __forceinline__ unsigned pkbf(float a, float b) {
  union { __hip_bfloat162 h; unsigned u; } c;
  c.h = __float22bfloat162_rn(make_float2(a, b));
  return c.u;
}
__device__ __forceinline__ void up2(unsigned u, float& lo, float& hi) {
  union { unsigned x; float f; } a, b;
  a.x = u << 16; b.x = u & 0xffff0000u; lo = a.f; hi = b.f;
}

// ---------------------------------------------------------------------------
// Fragment-major weight layout: for weight W[k=0..255][n], tile T=n>>4:
// frag[((T*8+kt)*64+lane)*8 + j] = bf16(W[kt*32+(lane>>4)*8+j][T*16+(lane&15)])
// ---------------------------------------------------------------------------
#define NFRAG 18

struct PreArgs {
  const float* fsrc[NFRAG];
  u16* fdst[NFRAG];
  int fstride[NFRAG];
  int fbase[NFRAG + 1];
  int fragTiles, hBase, prepBid, q1Bid;
  const float *x, *ginW, *ginb;
  u16* h_bf;
  const float *mbk, *mbv, *mbq, *S, *mWq;
  float *bkv0, *bqkv1, *bqkv2;
  u16* q1b;
  int* bar;
};

// k_pre: frag-tile transpose / gin GEMV / bias prep (+bar zero) / q1
__global__ __launch_bounds__(256) void k_pre(PreArgs a) {
  __shared__ __align__(16) char smem[27648];
  const int bid = blockIdx.x, t = threadIdx.x;

  if (bid < a.fragTiles) {
    u16* ld = (u16*)smem;  // 256*20*2 = 10240
    int j = 0;
    while (j + 1 < NFRAG && a.fbase[j + 1] <= bid) j++;
    const int localT = bid - a.fbase[j];
    const float* src = a.fsrc[j];
    const int Ns = a.fstride[j];
    const int n0 = localT * 16;
    {
      const float* s = src + (size_t)t * Ns + n0;
      const float4 v0 = ((const float4*)s)[0], v1 = ((const float4*)s)[1];
      const float4 v2 = ((const float4*)s)[2], v3 = ((const float4*)s)[3];
      unsigned* row = (unsigned*)(ld + t * 20);
      row[0] = pkbf(v0.x, v0.y); row[1] = pkbf(v0.z, v0.w);
      row[2] = pkbf(v1.x, v1.y); row[3] = pkbf(v1.z, v1.w);
      row[4] = pkbf(v2.x, v2.y); row[5] = pkbf(v2.z, v2.w);
      row[6] = pkbf(v3.x, v3.y); row[7] = pkbf(v3.z, v3.w);
    }
    __syncthreads();
    u16* dst = a.fdst[j] + (size_t)localT * 4096;
#pragma unroll
    for (int s2 = 0; s2 < 2; s2++) {
      const int o = t * 2 + s2, kt = o >> 6, lane = o & 63;
      const int nlo = lane & 15, bk = kt * 32 + ((lane >> 4) << 3);
      union { u16 h[8]; uint4 q; } pk;
#pragma unroll
      for (int j2 = 0; j2 < 8; j2++) pk.h[j2] = ld[(bk + j2) * 20 + nlo];
      *(uint4*)(dst + (size_t)(kt * 64 + lane) * 8) = pk.q;
    }
    return;
  }
  if (bid < a.prepBid) {
    float (*xs)[48] = (float (*)[48])(smem + 10240);
    const int row0 = (bid - a.hBase) * 4;
    if (t < 192) {
      const int rr = t / 48, k = t % 48;
      xs[rr][k] = a.x[(size_t)(row0 + rr) * 48 + k];
    }
    __syncthreads();
    const float bias = a.ginb[t];
    float acc[4] = {bias, bias, bias, bias};
    for (int k = 0; k < 48; k++) {
      const float w = a.ginW[(size_t)k * 256 + t];
#pragma unroll
      for (int rr = 0; rr < 4; rr++) acc[rr] += xs[rr][k] * w;
    }
#pragma unroll
    for (int rr = 0; rr < 4; rr++) a.h_bf[(size_t)(row0 + rr) * 256 + t] = f2b(acc[rr]);
    return;
  }
  if (bid == a.prepBid) {
    a.bar[t] = 0;  // zero all group-barrier counters (256 ints)
    a.bkv0[t] = a.mbk[t]; a.bkv0[256 + t] = a.mbv[t];
    a.bqkv1[t] = a.mbq[256 + t]; a.bqkv1[256 + t] = a.mbk[256 + t]; a.bqkv1[512 + t] = a.mbv[256 + t];
    a.bqkv2[t] = a.mbq[512 + t]; a.bqkv2[256 + t] = a.mbk[512 + t]; a.bqkv2[512 + t] = a.mbv[512 + t];
    return;
  }
  if (bid == a.q1Bid) {
    float* Ss = (float*)(smem + 11264);  // 16384
    for (int idx = t; idx < 4096; idx += 256) Ss[idx] = a.S[idx];
    __syncthreads();
    float acc[16];
#pragma unroll
    for (int r = 0; r < 16; r++) acc[r] = 0.f;
    for (int k = 0; k < 256; k++) {
      const float w = a.mWq[(size_t)k * 256 + t];
#pragma unroll
      for (int r = 0; r < 16; r++) acc[r] += Ss[r * 256 + k] * w;
    }
    const float bq = a.mbq[t];
#pragma unroll
    for (int r = 0; r < 16; r++) a.q1b[r * 256 + t] = f2b(acc[r] + bq);
    return;
  }
}

// ---------------------------------------------------------------------------
// hWiWj GEMM: writes hWi as fp32 (1024x256) and hWj as bf16 (1024x256).
// ---------------------------------------------------------------------------
__global__ __launch_bounds__(256) void k_wiwj(
    const u16* __restrict__ h, const u16* __restrict__ frag,
    float* __restrict__ hWiF, u16* __restrict__ hWjB) {
  __shared__ __align__(16) u16 As[64 * 264];
  const int t = threadIdx.x, lane = t & 63, wv = t >> 6;
  const int m0 = blockIdx.x * 64, n0 = blockIdx.y * 128;
  {
    const int row = t >> 2, ch = t & 3;
#pragma unroll
    for (int s = 0; s < 8; s++)
      *(uint4*)(As + row * 264 + ch * 64 + s * 8) =
          *(const uint4*)(h + (size_t)(m0 + row) * 256 + ch * 64 + s * 8);
  }
  __syncthreads();
  f4v acc[4][2];
#pragma unroll
  for (int mt = 0; mt < 4; mt++)
#pragma unroll
    for (int nt = 0; nt < 2; nt++) acc[mt][nt] = (f4v){0.f, 0.f, 0.f, 0.f};
  const int Tw = (n0 >> 4) + wv * 2;
#pragma unroll
  for (int kt = 0; kt < 8; kt++) {
    bf8v af[4], bf[2];
#pragma unroll
    for (int mt = 0; mt < 4; mt++)
      af[mt] = *(const bf8v*)(As + (mt * 16 + (lane & 15)) * 264 + kt * 32 + ((lane >> 4) << 3));
#pragma unroll
    for (int nt = 0; nt < 2; nt++)
      bf[nt] = *(const bf8v*)(frag + ((size_t)((Tw + nt) * 8 + kt) * 64 + lane) * 8);
#pragma unroll
    for (int mt = 0; mt < 4; mt++)
#pragma unroll
      for (int nt = 0; nt < 2; nt++)
        acc[mt][nt] = __builtin_amdgcn_mfma_f32_16x16x32_bf16(af[mt], bf[nt], acc[mt][nt], 0, 0, 0);
  }
#pragma unroll
  for (int mt = 0; mt < 4; mt++)
#pragma unroll
    for (int nt = 0; nt < 2; nt++) {
      const int n = n0 + wv * 32 + nt * 16 + (lane & 15);
      const int mb = m0 + mt * 16 + ((lane >> 4) << 2);
#pragma unroll
      for (int r = 0; r < 4; r++) {
        if (n < 256)
          hWiF[(size_t)(mb + r) * 256 + n] = acc[mt][nt][r];
        else
          hWjB[(size_t)(mb + r) * 256 + (n - 256)] = f2b(acc[mt][nt][r]);
      }
    }
}

// ---------------------------------------------------------------------------
// Edge MLP + masked aggregation. (256,2): no spill (round-5 proven).
// ---------------------------------------------------------------------------
__global__ __launch_bounds__(256, 2) void k_edge(
    const float* __restrict__ hWiF, const u16* __restrict__ hWjB,
    const float* __restrict__ adj, const float* __restrict__ geb1,
    const u16* __restrict__ fragW2, const float* __restrict__ geb2,
    u16* __restrict__ aggB) {
  __shared__ __align__(16) u16 As[64 * 280];
  __shared__ float hi[256];
  __shared__ int jlist[256];
  __shared__ int cnt;
  const int t = threadIdx.x, lane = t & 63, wv = t >> 6;
  const int b = blockIdx.x >> 8, i = blockIdx.x & 255;
  if (t == 0) cnt = 0;
  __syncthreads();
  {
    const float a = adj[(size_t)(b * 256 + i) * 256 + t];
    hi[t] = hWiF[(size_t)(b * 256 + i) * 256 + t] + geb1[t];
    if (a != 0.f) { const int p = atomicAdd(&cnt, 1); jlist[p] = t; }
  }
  __syncthreads();
  const int nact = cnt;
  if (nact == 0) {
    if (lane < 16) {
#pragma unroll
      for (int nt = 0; nt < 4; nt++)
        aggB[(size_t)(b * 256 + i) * 256 + wv * 64 + nt * 16 + lane] = 0;
    }
    return;
  }
  const int nch = (nact + 63) >> 6;
  float bias2[4];
#pragma unroll
  for (int nt = 0; nt < 4; nt++) bias2[nt] = geb2[wv * 64 + nt * 16 + (lane & 15)];
  float aggAcc[4] = {0.f, 0.f, 0.f, 0.f};
  const u16* fw = fragW2 + lane * 8;

  for (int c = 0; c < nch; c++) {
    const int rows = min(64, nact - c * 64);
    {  // build A chunk: relu(bf16(hWj[j]) + hi) -> bf16
      const int r = t >> 2, q = t & 3;
      const bool valid = (r < rows);
      const int j = valid ? jlist[c * 64 + r] : jlist[0];
      const uint4* s4 = (const uint4*)(hWjB + (size_t)(b * 256 + j) * 256 + q * 64);
      u16* dstrow = As + r * 280 + q * 72;
#pragma unroll
      for (int ii = 0; ii < 8; ii++) {
        const uint4 v = s4[ii];
        const int k = q * 64 + ii * 8;
        float f0, f1, f2, f3, f4, f5, f6, f7;
        up2(v.x, f0, f1); up2(v.y, f2, f3); up2(v.z, f4, f5); up2(v.w, f6, f7);
        uint4 qd;
        qd.x = pkbf(fmaxf(f0 + hi[k + 0], 0.f), fmaxf(f1 + hi[k + 1], 0.f));
        qd.y = pkbf(fmaxf(f2 + hi[k + 2], 0.f), fmaxf(f3 + hi[k + 3], 0.f));
        qd.z = pkbf(fmaxf(f4 + hi[k + 4], 0.f), fmaxf(f5 + hi[k + 5], 0.f));
        qd.w = pkbf(fmaxf(f6 + hi[k + 6], 0.f), fmaxf(f7 + hi[k + 7], 0.f));
        *(uint4*)(dstrow + ii * 8) = qd;
      }
    }
    __syncthreads();
    f4v acc[4][4];
#pragma unroll
    for (int jt = 0; jt < 4; jt++)
#pragma unroll
      for (int nt = 0; nt < 4; nt++) acc[jt][nt] = (f4v){0.f, 0.f, 0.f, 0.f};
    bf8v bcur[4];
#pragma unroll
    for (int nt = 0; nt < 4; nt++)
      bcur[nt] = *(const bf8v*)(fw + (size_t)((wv * 4 + nt) * 8 + 0) * 512);
#pragma unroll
    for (int kt = 0; kt < 8; kt++) {
      bf8v bnxt[4];
      if (kt < 7) {
#pragma unroll
        for (int nt = 0; nt < 4; nt++)
          bnxt[nt] = *(const bf8v*)(fw + (size_t)((wv * 4 + nt) * 8 + kt + 1) * 512);
      }
      bf8v af[4];
      const int coff = (kt >> 1) * 72 + (kt & 1) * 32 + ((lane >> 4) << 3);
#pragma unroll
      for (int jt = 0; jt < 4; jt++)
        af[jt] = *(const bf8v*)(As + (jt * 16 + (lane & 15)) * 280 + coff);
#pragma unroll
      for (int nt = 0; nt < 4; nt++)
#pragma unroll
        for (int jt = 0; jt < 4; jt++)
          acc[jt][nt] = __builtin_amdgcn_mfma_f32_16x16x32_bf16(af[jt], bcur[nt], acc[jt][nt], 0, 0, 0);
      if (kt < 7) {
#pragma unroll
        for (int nt = 0; nt < 4; nt++) bcur[nt] = bnxt[nt];
      }
    }
    const int rbase = (lane >> 4) * 4;
#pragma unroll
    for (int nt = 0; nt < 4; nt++) {
      float s = 0.f;
#pragma unroll
      for (int jt = 0; jt < 4; jt++) {
        const int r0 = jt * 16 + rbase;
#pragma unroll
        for (int r = 0; r < 4; r++) {
          const float e = fmaxf(acc[jt][nt][r] + bias2[nt], 0.f);
          s += (r0 + r < rows) ? e : 0.f;
        }
      }
      s += __shfl_xor(s, 16);
      s += __shfl_xor(s, 32);
      aggAcc[nt] += s;
    }
    __syncthreads();
  }
  if (lane < 16) {
#pragma unroll
    for (int nt = 0; nt < 4; nt++) {
      const int n = wv * 64 + nt * 16 + lane;
      aggB[(size_t)(b * 256 + i) * 256 + n] = f2b(aggAcc[nt]);
    }
  }
}

// ---------------------------------------------------------------------------
// Merged tail: 64 blocks x 1024 threads, FOUR independent per-batch pipelines
// of 16 blocks each (group g = bid>>4, member m = bid&15), group-local
// arrive/wait barriers (round-9 proven). NEW: member-0 blocks prefetch the
// phase-3 fragment span (fQKV1..fFin, 1344KB contiguous in workspace) into
// their own XCD's L2 while phase 1 runs — round-9 occupancy decomposition
// showed ~35us (71% of tailM) in phase 3, ~2us/stage = cold-fetch latency.
// ---------------------------------------------------------------------------
__device__ __forceinline__ void barArrive(int* c) {
  __syncthreads();
  if (threadIdx.x == 0)
    __hip_atomic_fetch_add(c, 1, __ATOMIC_RELEASE, __HIP_MEMORY_SCOPE_AGENT);
}
__device__ __forceinline__ void barWait(int* c, int target) {
  if (threadIdx.x == 0) {
    int it = 0;
    while (__hip_atomic_load(c, __ATOMIC_ACQUIRE, __HIP_MEMORY_SCOPE_AGENT) < target) {
      __builtin_amdgcn_s_sleep(8);
      if (((++it) & 255) == 0)
        __hip_atomic_fetch_add(c, 0, __ATOMIC_ACQ_REL, __HIP_MEMORY_SCOPE_AGENT);
    }
  }
  __syncthreads();
}

// single-tile GEMM stage, 16 waves: wave w owns tile w; prefetched B-frag;
// per-tile kt-chain identical to round-0 helpers -> bitwise-identical.
__device__ void g16w(const u16* Al, const u16* __restrict__ frag,
                     const float* bias, int relu, u16* Ol, int t) {
  const int lane = t & 63, w = t >> 6;  // [0,16)
  f4v acc = (f4v){0.f, 0.f, 0.f, 0.f};
  const u16* abase = Al + (lane & 15) * 264 + ((lane >> 4) << 3);
  const u16* fb = frag + ((size_t)(w * 8) * 64 + lane) * 8;
  bf8v bc = *(const bf8v*)fb;
#pragma unroll
  for (int kt = 0; kt < 8; kt++) {
    bf8v bn;
    if (kt < 7) bn = *(const bf8v*)(fb + (size_t)(kt + 1) * 512);
    const bf8v af = *(const bf8v*)(abase + kt * 32);
    acc = __builtin_amdgcn_mfma_f32_16x16x32_bf16(af, bc, acc, 0, 0, 0);
    if (kt < 7) bc = bn;
  }
  const int col = w * 16 + (lane & 15);
  const float bv = bias[col];
#pragma unroll
  for (int r = 0; r < 4; r++) {
    const int row = ((lane >> 4) << 2) + r;
    float v = acc[r] + bv;
    if (relu) v = fmaxf(v, 0.f);
    Ol[row * 264 + col] = f2b(v);
  }
}

// KV stage, 16 waves x 2 tiles: wave w owns tiles {2w, 2w+1} (512 cols).
__device__ void g16kv2(const u16* Al, const u16* __restrict__ frag,
                       const float* bias, u16* outG, int t) {
  const int lane = t & 63, w = t >> 6;
  f4v acc[2];
  acc[0] = (f4v){0.f, 0.f, 0.f, 0.f};
  acc[1] = (f4v){0.f, 0.f, 0.f, 0.f};
  const u16* abase = Al + (lane & 15) * 264 + ((lane >> 4) << 3);
  const u16* f0 = frag + ((size_t)((w * 2 + 0) * 8) * 64 + lane) * 8;
  const u16* f1 = frag + ((size_t)((w * 2 + 1) * 8) * 64 + lane) * 8;
  bf8v bc0 = *(const bf8v*)f0;
  bf8v bc1 = *(const bf8v*)f1;
#pragma unroll
  for (int kt = 0; kt < 8; kt++) {
    bf8v bn0, bn1;
    if (kt < 7) {
      bn0 = *(const bf8v*)(f0 + (size_t)(kt + 1) * 512);
      bn1 = *(const bf8v*)(f1 + (size_t)(kt + 1) * 512);
    }
    const bf8v af = *(const bf8v*)(abase + kt * 32);
    acc[0] = __builtin_amdgcn_mfma_f32_16x16x32_bf16(af, bc0, acc[0], 0, 0, 0);
    acc[1] = __builtin_amdgcn_mfma_f32_16x16x32_bf16(af, bc1, acc[1], 0, 0, 0);
    if (kt < 7) { bc0 = bn0; bc1 = bn1; }
  }
#pragma unroll
  for (int nt = 0; nt < 2; nt++) {
    const int col = (w * 2 + nt) * 16 + (lane & 15);
    const float bv = bias[col];
#pragma unroll
    for (int r = 0; r < 4; r++) {
      const int row = ((lane >> 4) << 2) + r;
      outG[(size_t)row * 512 + col] = f2b(acc[nt][r] + bv);
    }
  }
}

// MAB1 attention, 8-row half (half=0: rows 0-7, half=1: rows 8-15); per-row
// arithmetic order identical to the full-tile original.
__device__ void attn_half(const u16* __restrict__ qbuf,
                          const u16* __restrict__ kbuf, const u16* __restrict__ vbuf,
                          float* __restrict__ oF, u16* __restrict__ oB,
                          int b, int hd, int half, float* qs, float* sc, float* vs, int t) {
  const int lane = t & 63, w = t >> 6;
  const int Lk = 256;
  if (t < 64) {  // load all 16 Q rows (only 8 used; harmless)
    const int row = t >> 2, part = t & 3;
    const uint4 q4 = *(const uint4*)(qbuf + (size_t)row * 256 + hd * 32 + part * 8);
    float f0, f1, f2, f3, f4, f5, f6, f7;
    up2(q4.x, f0, f1); up2(q4.y, f2, f3); up2(q4.z, f4, f5); up2(q4.w, f6, f7);
    float4* d = (float4*)(qs + row * 32 + part * 8);
    d[0] = make_float4(f0, f1, f2, f3);
    d[1] = make_float4(f4, f5, f6, f7);
  }
  __syncthreads();
  if (t < 256) {
    float kv[32];
    const uint4* kp = (const uint4*)(kbuf + (size_t)(b * Lk + t) * 512 + hd * 32);
#pragma unroll
    for (int c4 = 0; c4 < 4; c4++) {
      const uint4 k4 = kp[c4];
      up2(k4.x, kv[c4 * 8 + 0], kv[c4 * 8 + 1]);
      up2(k4.y, kv[c4 * 8 + 2], kv[c4 * 8 + 3]);
      up2(k4.z, kv[c4 * 8 + 4], kv[c4 * 8 + 5]);
      up2(k4.w, kv[c4 * 8 + 6], kv[c4 * 8 + 7]);
    }
    for (int r = 0; r < 8; r++) {
      const int grow = half * 8 + r;
      float s = 0.f;
#pragma unroll
      for (int d = 0; d < 32; d++) s += qs[grow * 32 + d] * kv[d];
      sc[r * 256 + t] = s * 0.0625f;
    }
  }
  __syncthreads();
  if (w < 8) {  // softmax: wave w handles local row w (identical shuffle ops)
    const int r = w;
    float v[4];
    float mx = -1e30f;
#pragma unroll
    for (int q2 = 0; q2 < 4; q2++) {
      v[q2] = sc[r * 256 + lane + q2 * 64];
      mx = fmaxf(mx, v[q2]);
    }
    for (int off = 32; off; off >>= 1) mx = fmaxf(mx, __shfl_xor(mx, off));
    float sum = 0.f;
#pragma unroll
    for (int q2 = 0; q2 < 4; q2++) { v[q2] = __expf(v[q2] - mx); sum += v[q2]; }
    for (int off = 32; off; off >>= 1) sum += __shfl_xor(sum, off);
    const float inv = 1.f / sum;
#pragma unroll
    for (int q2 = 0; q2 < 4; q2++) sc[r * 256 + lane + q2 * 64] = v[q2] * inv;
  }
  __syncthreads();
  {  // V load: 1024 threads cover 256 rows x 4 parts exactly
    const int row = t >> 2, part = t & 3;
    const uint4 v4 = *(const uint4*)(vbuf + (size_t)(b * Lk + row) * 512 + hd * 32 + part * 8);
    float f0, f1, f2, f3, f4, f5, f6, f7;
    up2(v4.x, f0, f1); up2(v4.y, f2, f3); up2(v4.z, f4, f5); up2(v4.w, f6, f7);
    float4* d = (float4*)(vs + row * 32 + part * 8);
    d[0] = make_float4(f0, f1, f2, f3);
    d[1] = make_float4(f4, f5, f6, f7);
  }
  __syncthreads();
  if (t < 256) {  // PV: local row r0 = t>>5 in [0,8), same j-order
    const int r0 = t >> 5, d = t & 31;
    const int grow = half * 8 + r0;
    float a0 = qs[grow * 32 + d];
#pragma unroll 4
    for (int j = 0; j < Lk; j++) a0 += sc[r0 * 256 + j] * vs[j * 32 + d];
    const int c0 = hd * 32 + d;
    oF[(size_t)(b * 16 + grow) * 256 + c0] = a0;
    oB[(size_t)(b * 16 + grow) * 256 + c0] = f2b(a0);
  }
}

// ---- LDS-local single-tile helpers (round-0 proven numerics) ----
__device__ void wprojG(const u16* __restrict__ o1b, const float* __restrict__ o1f,
                       const u16* __restrict__ frag, const float* __restrict__ bias,
                       u16* actL, float* residL, int b, int T, int lane) {
  f4v acc = (f4v){0.f, 0.f, 0.f, 0.f};
  const u16* abase = o1b + (size_t)(b * 16 + (lane & 15)) * 256 + ((lane >> 4) << 3);
  const u16* fbase = frag + ((size_t)(T * 8) * 64 + lane) * 8;
#pragma unroll
  for (int kt = 0; kt < 8; kt++)
    acc = __builtin_amdgcn_mfma_f32_16x16x32_bf16(*(const bf8v*)(abase + kt * 32),
                                                  *(const bf8v*)(fbase + (size_t)kt * 512), acc, 0, 0, 0);
  const int col = T * 16 + (lane & 15);
  const float bv = bias[col];
#pragma unroll
  for (int r = 0; r < 4; r++) {
    const int row = ((lane >> 4) << 2) + r;
    const float v = fmaxf(acc[r] + bv, 0.f) + o1f[(size_t)(b * 16 + row) * 256 + col];
    residL[row * 256 + col] = v;
    actL[row * 264 + col] = f2b(v);
  }
}

template <int NT>
__device__ __forceinline__ void wprojQn(
    const u16* actL, const u16* __restrict__ frag,
    const float* __restrict__ bias, u16* qkvL, int T0, int lane) {
  f4v acc[NT];
#pragma unroll
  for (int nt = 0; nt < NT; nt++) acc[nt] = (f4v){0.f, 0.f, 0.f, 0.f};
  const u16* abase = actL + (lane & 15) * 264 + ((lane >> 4) << 3);
#pragma unroll
  for (int kt = 0; kt < 8; kt++) {
    const bf8v af = *(const bf8v*)(abase + kt * 32);
#pragma unroll
    for (int nt = 0; nt < NT; nt++) {
      const bf8v bf = *(const bf8v*)(frag + ((size_t)((T0 + nt) * 8 + kt) * 64 + lane) * 8);
      acc[nt] = __builtin_amdgcn_mfma_f32_16x16x32_bf16(af, bf, acc[nt], 0, 0, 0);
    }
  }
#pragma unroll
  for (int nt = 0; nt < NT; nt++) {
    const int col = (T0 + nt) * 16 + (lane & 15);
    const float bv = bias[col];
#pragma unroll
    for (int r = 0; r < 4; r++) {
      const int row = ((lane >> 4) << 2) + r;
      qkvL[row * 776 + col] = f2b(acc[nt][r] + bv);
    }
  }
}

__device__ void wprojR(const u16* actIn, const u16* __restrict__ frag,
                       const float* __restrict__ bias, u16* actOut, float* residL,
                       int T, int lane) {
  f4v acc = (f4v){0.f, 0.f, 0.f, 0.f};
  const u16* abase = actIn + (lane & 15) * 264 + ((lane >> 4) << 3);
  const u16* fbase = frag + ((size_t)(T * 8) * 64 + lane) * 8;
#pragma unroll
  for (int kt = 0; kt < 8; kt++)
    acc = __builtin_amdgcn_mfma_f32_16x16x32_bf16(*(const bf8v*)(abase + kt * 32),
                                                  *(const bf8v*)(fbase + (size_t)kt * 512), acc, 0, 0, 0);
  const int col = T * 16 + (lane & 15);
  const float bv = bias[col];
#pragma unroll
  for (int r = 0; r < 4; r++) {
    const int row = ((lane >> 4) << 2) + r;
    const float v = fmaxf(acc[r] + bv, 0.f) + residL[row * 256 + col];
    residL[row * 256 + col] = v;
    actOut[row * 264 + col] = f2b(v);
  }
}

__device__ void wprojF(const u16* actL, const u16* __restrict__ frag,
                       const float* __restrict__ bias, float* __restrict__ outG,
                       int T, int lane) {
  f4v acc = (f4v){0.f, 0.f, 0.f, 0.f};
  const u16* abase = actL + (lane & 15) * 264 + ((lane >> 4) << 3);
  const u16* fbase = frag + ((size_t)(T * 8) * 64 + lane) * 8;
#pragma unroll
  for (int kt = 0; kt < 8; kt++)
    acc = __builtin_amdgcn_mfma_f32_16x16x32_bf16(*(const bf8v*)(abase + kt * 32),
                                                  *(const bf8v*)(fbase + (size_t)kt * 512), acc, 0, 0, 0);
  const int col = T * 16 + (lane & 15);
  const float bv = bias[col];
#pragma unroll
  for (int r = 0; r < 4; r++) {
    const int row = ((lane >> 4) << 2) + r;
    outG[(size_t)row * 384 + col] = acc[r] + bv;
  }
}

__device__ void attnB(const u16* qkvL, float* residL, u16* actOut, float* ps,
                      int hd, int lane) {
  const int r = lane & 15, cg = lane >> 4;
  float qv[32];
  {
    const uint4* qp = (const uint4*)(qkvL + r * 776 + hd * 32);
#pragma unroll
    for (int c4 = 0; c4 < 4; c4++) {
      const uint4 q4 = qp[c4];
      up2(q4.x, qv[c4 * 8 + 0], qv[c4 * 8 + 1]);
      up2(q4.y, qv[c4 * 8 + 2], qv[c4 * 8 + 3]);
      up2(q4.z, qv[c4 * 8 + 4], qv[c4 * 8 + 5]);
      up2(q4.w, qv[c4 * 8 + 6], qv[c4 * 8 + 7]);
    }
  }
  float p[4];
#pragma unroll
  for (int c = 0; c < 4; c++) {
    const int cc = cg * 4 + c;
    const uint4* kp = (const uint4*)(qkvL + cc * 776 + 256 + hd * 32);
    float s = 0.f;
#pragma unroll
    for (int c4 = 0; c4 < 4; c4++) {
      const uint4 k4 = kp[c4];
      float k0, k1;
      up2(k4.x, k0, k1); s += qv[c4 * 8 + 0] * k0 + qv[c4 * 8 + 1] * k1;
      up2(k4.y, k0, k1); s += qv[c4 * 8 + 2] * k0 + qv[c4 * 8 + 3] * k1;
      up2(k4.z, k0, k1); s += qv[c4 * 8 + 4] * k0 + qv[c4 * 8 + 5] * k1;
      up2(k4.w, k0, k1); s += qv[c4 * 8 + 6] * k0 + qv[c4 * 8 + 7] * k1;
    }
    p[c] = s * 0.0625f;
  }
  float mx = fmaxf(fmaxf(p[0], p[1]), fmaxf(p[2], p[3]));
  mx = fmaxf(mx, __shfl_xor(mx, 16));
  mx = fmaxf(mx, __shfl_xor(mx, 32));
  float sum = 0.f;
#pragma unroll
  for (int c = 0; c < 4; c++) { p[c] = __expf(p[c] - mx); sum += p[c]; }
  sum += __shfl_xor(sum, 16);
  sum += __shfl_xor(sum, 32);
  const float inv = 1.f / sum;
#pragma unroll
  for (int c = 0; c < 4; c++) ps[r * 16 + cg * 4 + c] = p[c] * inv;
  float o[8];
#pragma unroll
  for (int j = 0; j < 8; j++) o[j] = qv[cg * 8 + j];
#pragma unroll
  for (int c = 0; c < 16; c++) {
    const float pv = ps[r * 16 + c];
    const uint4 v4 = *(const uint4*)(qkvL + c * 776 + 512 + hd * 32 + cg * 8);
    float v0, v1;
    up2(v4.x, v0, v1); o[0] += pv * v0; o[1] += pv * v1;
    up2(v4.y, v0, v1); o[2] += pv * v0; o[3] += pv * v1;
    up2(v4.z, v0, v1); o[4] += pv * v0; o[5] += pv * v1;
    up2(v4.w, v0, v1); o[6] += pv * v0; o[7] += pv * v1;
  }
  const int col0 = hd * 32 + cg * 8;
#pragma unroll
  for (int j = 0; j < 8; j++) residL[r * 256 + col0 + j] = o[j];
  unsigned* ob = (unsigned*)(actOut + r * 264 + col0);
  ob[0] = pkbf(o[0], o[1]); ob[1] = pkbf(o[2], o[3]);
  ob[2] = pkbf(o[4], o[5]); ob[3] = pkbf(o[6], o[7]);
}

struct TailArgs {
  const u16 *agg, *fGn1, *fGn2, *fGo, *fKV0, *fQKV1, *fQKV2, *fO0, *fO1, *fO2, *fFin, *q1b;
  const float *gnb1, *gnb2, *gob, *bkv0, *bqkv1, *bqkv2, *mbo, *finb;
  u16 *kv1, *o1b;
  float *o1f, *outF;
  const unsigned* pf3;  // phase-3 fragment span base (= fQKV1; contiguous thru fFin)
  int* bar;
};

// Merged tail kernel: 4 per-batch pipelines x 16 blocks.
__global__ __launch_bounds__(1024) void k_tailM(TailArgs a) {
  __shared__ __align__(16) char smem[58112];
  const int bid = blockIdx.x, t = threadIdx.x;
  const int lane = t & 63, w = t >> 6;
  const int g = bid >> 4, m = bid & 15;
  int* c1 = a.bar + g * 32;       // phase1-done counter (own 64B line)
  int* c2 = a.bar + g * 32 + 16;  // phase2-done counter (own 64B line)

  // Phase-3 L2 prefetch: member 0 touches 1 dword per 128B line of the
  // 1344KB fQKV1..fFin span (10752 lines / 1024 thr = ~11 loads/thread),
  // warming its own XCD's L2 while phase 1 computes. asm keeps loads live
  // (guide rule #17); no numerics impact.
  unsigned pfacc = 0;
  if (m == 0) {
    for (int i = t; i < 10752; i += 1024) pfacc ^= a.pf3[(size_t)i * 32];
    asm volatile("" :: "v"(pfacc));
  }

  {  // ---- phase 1: node MLP + KV0 (16 rows per block) ----
    u16* actA = (u16*)smem;
    u16* actB = (u16*)(smem + 8448);
    const int r0 = bid * 16;
    if (t < 512) {
      const int row = t >> 5, ch = t & 31;
      *(uint4*)(actA + row * 264 + ch * 8) =
          *(const uint4*)(a.agg + (size_t)(r0 + row) * 256 + ch * 8);
    }
    __syncthreads();
    g16w(actA, a.fGn1, a.gnb1, 1, actB, t); __syncthreads();
    g16w(actB, a.fGn2, a.gnb2, 1, actA, t); __syncthreads();
    g16w(actA, a.fGo, a.gob, 0, actB, t); __syncthreads();
    g16kv2(actB, a.fKV0, a.bkv0, a.kv1 + (size_t)r0 * 512, t);
  }
  barArrive(c1);
  barWait(c1, 16);
  {  // ---- phase 2: MAB1 attention, head m&7, half m>>3 ----
    float* qs = (float*)smem;
    float* sc = (float*)(smem + 2048);
    float* vs = (float*)(smem + 18432);
    attn_half(a.q1b, a.kv1, a.kv1 + 256, a.o1f, a.o1b,
              g, m & 7, m >> 3, qs, sc, vs, t);
  }
  barArrive(c2);
  if (m != 0) return;
  barWait(c2, 16);
  {  // ---- phase 3: MAB2 + MAB3 + final for batch g (16 waves) ----
    const int b = g;
    u16* act0 = (u16*)smem;                  // 8448
    u16* act1 = (u16*)(smem + 8448);         // 8448
    u16* qkvL = (u16*)(smem + 16896);        // 24832
    float* residL = (float*)(smem + 41728);  // 16384 (ends 58112)
    float* psL = (float*)smem;               // aliases dead act0
    wprojG(a.o1b, a.o1f, a.fO0, a.mbo, act0, residL, b, w, lane);
    __syncthreads();
    wprojQn<3>(act0, a.fQKV1, a.bqkv1, qkvL, w * 3, lane);
    __syncthreads();
    if (w < 8) attnB(qkvL, residL, act1, psL + w * 256, w, lane);
    __syncthreads();
    wprojR(act1, a.fO1, a.mbo + 256, act0, residL, w, lane);
    __syncthreads();
    wprojQn<3>(act0, a.fQKV2, a.bqkv2, qkvL, w * 3, lane);
    __syncthreads();
    if (w < 8) attnB(qkvL, residL, act1, psL + w * 256, w, lane);
    __syncthreads();
    wprojR(act1, a.fO2, a.mbo + 512, act0, residL, w, lane);
    __syncthreads();
    for (int T = w; T < 24; T += 16)
      wprojF(act0, a.fFin, a.finb, a.outF + (size_t)b * 16 * 384, T, lane);
  }
}

// ---------------------------------------------------------------------------
extern "C" void kernel_launch(void* const* d_in, const int* in_sizes, int n_in,
                              void* d_out, int out_size, void* d_ws, size_t ws_size,
                              hipStream_t stream) {
  const float* x    = (const float*)d_in[0];
  const float* adj  = (const float*)d_in[1];
  const float* ginW = (const float*)d_in[2];
  const float* ginb = (const float*)d_in[3];
  const float* geW1 = (const float*)d_in[4];
  const float* geb1 = (const float*)d_in[5];
  const float* geW2 = (const float*)d_in[6];
  const float* geb2 = (const float*)d_in[7];
  const float* gnW1 = (const float*)d_in[8];
  const float* gnb1 = (const float*)d_in[9];
  const float* gnW2 = (const float*)d_in[10];
  const float* gnb2 = (const float*)d_in[11];
  const float* goW  = (const float*)d_in[12];
  const float* gob  = (const float*)d_in[13];
  const float* S    = (const float*)d_in[14];
  const float* mWq  = (const float*)d_in[15];
  const float* mbq  = (const float*)d_in[16];
  const float* mWk  = (const float*)d_in[17];
  const float* mbk  = (const float*)d_in[18];
  const float* mWv  = (const float*)d_in[19];
  const float* mbv  = (const float*)d_in[20];
  const float* mWo  = (const float*)d_in[21];
  const float* mbo  = (const float*)d_in[22];
  const float* finW = (const float*)d_in[23];
  const float* finb = (const float*)d_in[24];
  (void)in_sizes; (void)n_in; (void)out_size; (void)ws_size;

  char* wp = (char*)d_ws;
  size_t off = 0;
  auto alloc = [&](size_t bytes) -> char* {
    char* p = wp + off;
    off += (bytes + 255) & ~(size_t)255;
    return p;
  };
  u16* h_bf     = (u16*)alloc(1024 * 256 * 2);
  float* hWiF   = (float*)alloc((size_t)1024 * 256 * 4);
  u16* hWjB     = (u16*)alloc(1024 * 256 * 2);
  u16* fWiWj    = (u16*)alloc(512 * 256 * 2);
  u16* fW2      = (u16*)alloc(256 * 256 * 2);
  u16* fGn1     = (u16*)alloc(256 * 256 * 2);
  u16* fGn2     = (u16*)alloc(256 * 256 * 2);
  u16* fGo      = (u16*)alloc(256 * 256 * 2);
  u16* fKV0     = (u16*)alloc(512 * 256 * 2);
  // NOTE: fQKV1..fFin must stay CONTIGUOUS (each size is a multiple of 256,
  // so alloc() inserts no padding) — k_tailM prefetches this 1344KB span.
  u16* fQKV1    = (u16*)alloc(768 * 256 * 2);
  u16* fQKV2    = (u16*)alloc(768 * 256 * 2);
  u16* fO0      = (u16*)alloc(256 * 256 * 2);
  u16* fO1      = (u16*)alloc(256 * 256 * 2);
  u16* fO2      = (u16*)alloc(256 * 256 * 2);
  u16* fFin     = (u16*)alloc(384 * 256 * 2);
  float* bkv0   = (float*)alloc(512 * 4);
  float* bqkv1  = (float*)alloc(768 * 4);
  float* bqkv2  = (float*)alloc(768 * 4);
  u16* q1b      = (u16*)alloc(16 * 256 * 2);
  u16* agg_b    = (u16*)alloc(1024 * 256 * 2);
  u16* kv1      = (u16*)alloc(1024 * 512 * 2);
  float* o1f    = (float*)alloc(64 * 256 * 4);
  u16* o1b      = (u16*)alloc(64 * 256 * 2);
  int* bar      = (int*)alloc(1024);

  PreArgs P{};
  int nj = 0, tiles = 0;
  auto addF = [&](const float* s, int stride, u16* d, int nT) {
    P.fsrc[nj] = s; P.fdst[nj] = d; P.fstride[nj] = stride; P.fbase[nj] = tiles;
    tiles += nT; nj++;
  };
  addF(geW1, 256, fWiWj, 16);
  addF(geW1 + 65536, 256, fWiWj + 16 * 4096, 16);
  addF(geW2, 256, fW2, 16);
  addF(gnW1, 256, fGn1, 16);
  addF(gnW2, 256, fGn2, 16);
  addF(goW, 256, fGo, 16);
  addF(mWk, 256, fKV0, 16);
  addF(mWv, 256, fKV0 + 16 * 4096, 16);
  addF(mWq + 65536, 256, fQKV1, 16);
  addF(mWk + 65536, 256, fQKV1 + 16 * 4096, 16);
  addF(mWv + 65536, 256, fQKV1 + 32 * 4096, 16);
  addF(mWq + 131072, 256, fQKV2, 16);
  addF(mWk + 131072, 256, fQKV2 + 16 * 4096, 16);
  addF(mWv + 131072, 256, fQKV2 + 32 * 4096, 16);
  addF(mWo, 256, fO0, 16);
  addF(mWo + 65536, 256, fO1, 16);
  addF(mWo + 131072, 256, fO2, 16);
  addF(finW, 384, fFin, 24);
  P.fbase[nj] = tiles;
  P.fragTiles = tiles;        // 296
  P.hBase = tiles;
  P.prepBid = tiles + 256;    // 552
  P.q1Bid = tiles + 257;      // 553
  P.x = x; P.ginW = ginW; P.ginb = ginb; P.h_bf = h_bf;
  P.mbk = mbk; P.mbv = mbv; P.mbq = mbq; P.S = S; P.mWq = mWq;
  P.bkv0 = bkv0; P.bqkv1 = bqkv1; P.bqkv2 = bqkv2; P.q1b = q1b;
  P.bar = bar;

  TailArgs T{};
  T.agg = agg_b; T.fGn1 = fGn1; T.fGn2 = fGn2; T.fGo = fGo; T.fKV0 = fKV0;
  T.fQKV1 = fQKV1; T.fQKV2 = fQKV2; T.fO0 = fO0; T.fO1 = fO1; T.fO2 = fO2;
  T.fFin = fFin; T.q1b = q1b;
  T.gnb1 = gnb1; T.gnb2 = gnb2; T.gob = gob;
  T.bkv0 = bkv0; T.bqkv1 = bqkv1; T.bqkv2 = bqkv2; T.mbo = mbo; T.finb = finb;
  T.kv1 = kv1; T.o1b = o1b; T.o1f = o1f; T.outF = (float*)d_out;
  T.pf3 = (const unsigned*)fQKV1;
  T.bar = bar;

  k_pre<<<dim3(tiles + 258), dim3(256), 0, stream>>>(P);
  k_wiwj<<<dim3(16, 4), dim3(256), 0, stream>>>(h_bf, fWiWj, hWiF, hWjB);
  k_edge<<<dim3(1024), dim3(256), 0, stream>>>(hWiF, hWjB, adj, geb1, fW2, geb2, agg_b);
  k_tailM<<<dim3(64), dim3(1024), 0, stream>>>(T);
}

// Round 11
// 218.590 us; speedup vs baseline: 1.0338x; 1.0338x over previous
//
#include <hip/hip_runtime.h>
#include <hip/hip_bf16.h>

typedef unsigned short u16;
typedef __bf16 bf8v __attribute__((ext_vector_type(8)));
typedef float f4v __attribute__((ext_vector_type(4)));

__device__ __forceinline__ float b2f(u16 v) {
  union { unsigned u; float f; } x; x.u = ((unsigned)v) << 16; return x.f;
}
__device__ __forceinline__ u16 f2b(float f) {
  union { float f; unsigned u; } x; x.f = f;
  unsigned r = (x.u + 0x7FFFu + ((x.u >> 16) & 1u)) >> 16;
  return (u16)r;
}
__device__ __forceinline__ unsigned pkbf(float a, float b) {
  union { __hip_bfloat162 h; unsigned u; } c;
  c.h = __float22bfloat162_rn(make_float2(a, b));
  return c.u;
}
__device__ __forceinline__ void up2(unsigned u, float& lo, float& hi) {
  union { unsigned x; float f; } a, b;
  a.x = u << 16; b.x = u & 0xffff0000u; lo = a.f; hi = b.f;
}

// ---------------------------------------------------------------------------
// Fragment-major weight layout: for weight W[k=0..255][n], tile T=n>>4:
// frag[((T*8+kt)*64+lane)*8 + j] = bf16(W[kt*32+(lane>>4)*8+j][T*16+(lane&15)])
// ---------------------------------------------------------------------------
#define NFRAG 18

struct PreArgs {
  const float* fsrc[NFRAG];
  u16* fdst[NFRAG];
  int fstride[NFRAG];
  int fbase[NFRAG + 1];
  int fragTiles, hBase, prepBid, q1Bid;
  const float *x, *ginW, *ginb;
  u16* h_bf;
  const float *mbk, *mbv, *mbq, *S, *mWq;
  float *bkv0, *bqkv1, *bqkv2;
  u16* q1b;
  int* bar;
};

// k_pre: frag-tile transpose / gin GEMV / bias prep (+bar zero) / q1
__global__ __launch_bounds__(256) void k_pre(PreArgs a) {
  __shared__ __align__(16) char smem[27648];
  const int bid = blockIdx.x, t = threadIdx.x;

  if (bid < a.fragTiles) {
    u16* ld = (u16*)smem;  // 256*20*2 = 10240
    int j = 0;
    while (j + 1 < NFRAG && a.fbase[j + 1] <= bid) j++;
    const int localT = bid - a.fbase[j];
    const float* src = a.fsrc[j];
    const int Ns = a.fstride[j];
    const int n0 = localT * 16;
    {
      const float* s = src + (size_t)t * Ns + n0;
      const float4 v0 = ((const float4*)s)[0], v1 = ((const float4*)s)[1];
      const float4 v2 = ((const float4*)s)[2], v3 = ((const float4*)s)[3];
      unsigned* row = (unsigned*)(ld + t * 20);
      row[0] = pkbf(v0.x, v0.y); row[1] = pkbf(v0.z, v0.w);
      row[2] = pkbf(v1.x, v1.y); row[3] = pkbf(v1.z, v1.w);
      row[4] = pkbf(v2.x, v2.y); row[5] = pkbf(v2.z, v2.w);
      row[6] = pkbf(v3.x, v3.y); row[7] = pkbf(v3.z, v3.w);
    }
    __syncthreads();
    u16* dst = a.fdst[j] + (size_t)localT * 4096;
#pragma unroll
    for (int s2 = 0; s2 < 2; s2++) {
      const int o = t * 2 + s2, kt = o >> 6, lane = o & 63;
      const int nlo = lane & 15, bk = kt * 32 + ((lane >> 4) << 3);
      union { u16 h[8]; uint4 q; } pk;
#pragma unroll
      for (int j2 = 0; j2 < 8; j2++) pk.h[j2] = ld[(bk + j2) * 20 + nlo];
      *(uint4*)(dst + (size_t)(kt * 64 + lane) * 8) = pk.q;
    }
    return;
  }
  if (bid < a.prepBid) {
    float (*xs)[48] = (float (*)[48])(smem + 10240);
    const int row0 = (bid - a.hBase) * 4;
    if (t < 192) {
      const int rr = t / 48, k = t % 48;
      xs[rr][k] = a.x[(size_t)(row0 + rr) * 48 + k];
    }
    __syncthreads();
    const float bias = a.ginb[t];
    float acc[4] = {bias, bias, bias, bias};
    for (int k = 0; k < 48; k++) {
      const float w = a.ginW[(size_t)k * 256 + t];
#pragma unroll
      for (int rr = 0; rr < 4; rr++) acc[rr] += xs[rr][k] * w;
    }
#pragma unroll
    for (int rr = 0; rr < 4; rr++) a.h_bf[(size_t)(row0 + rr) * 256 + t] = f2b(acc[rr]);
    return;
  }
  if (bid == a.prepBid) {
    a.bar[t] = 0;  // zero all group-barrier counters (256 ints)
    a.bkv0[t] = a.mbk[t]; a.bkv0[256 + t] = a.mbv[t];
    a.bqkv1[t] = a.mbq[256 + t]; a.bqkv1[256 + t] = a.mbk[256 + t]; a.bqkv1[512 + t] = a.mbv[256 + t];
    a.bqkv2[t] = a.mbq[512 + t]; a.bqkv2[256 + t] = a.mbk[512 + t]; a.bqkv2[512 + t] = a.mbv[512 + t];
    return;
  }
  if (bid == a.q1Bid) {
    float* Ss = (float*)(smem + 11264);  // 16384
    for (int idx = t; idx < 4096; idx += 256) Ss[idx] = a.S[idx];
    __syncthreads();
    float acc[16];
#pragma unroll
    for (int r = 0; r < 16; r++) acc[r] = 0.f;
    for (int k = 0; k < 256; k++) {
      const float w = a.mWq[(size_t)k * 256 + t];
#pragma unroll
      for (int r = 0; r < 16; r++) acc[r] += Ss[r * 256 + k] * w;
    }
    const float bq = a.mbq[t];
#pragma unroll
    for (int r = 0; r < 16; r++) a.q1b[r * 256 + t] = f2b(acc[r] + bq);
    return;
  }
}

// ---------------------------------------------------------------------------
// hWiWj GEMM: writes hWi as fp32 (1024x256) and hWj as bf16 (1024x256).
// ---------------------------------------------------------------------------
__global__ __launch_bounds__(256) void k_wiwj(
    const u16* __restrict__ h, const u16* __restrict__ frag,
    float* __restrict__ hWiF, u16* __restrict__ hWjB) {
  __shared__ __align__(16) u16 As[64 * 264];
  const int t = threadIdx.x, lane = t & 63, wv = t >> 6;
  const int m0 = blockIdx.x * 64, n0 = blockIdx.y * 128;
  {
    const int row = t >> 2, ch = t & 3;
#pragma unroll
    for (int s = 0; s < 8; s++)
      *(uint4*)(As + row * 264 + ch * 64 + s * 8) =
          *(const uint4*)(h + (size_t)(m0 + row) * 256 + ch * 64 + s * 8);
  }
  __syncthreads();
  f4v acc[4][2];
#pragma unroll
  for (int mt = 0; mt < 4; mt++)
#pragma unroll
    for (int nt = 0; nt < 2; nt++) acc[mt][nt] = (f4v){0.f, 0.f, 0.f, 0.f};
  const int Tw = (n0 >> 4) + wv * 2;
#pragma unroll
  for (int kt = 0; kt < 8; kt++) {
    bf8v af[4], bf[2];
#pragma unroll
    for (int mt = 0; mt < 4; mt++)
      af[mt] = *(const bf8v*)(As + (mt * 16 + (lane & 15)) * 264 + kt * 32 + ((lane >> 4) << 3));
#pragma unroll
    for (int nt = 0; nt < 2; nt++)
      bf[nt] = *(const bf8v*)(frag + ((size_t)((Tw + nt) * 8 + kt) * 64 + lane) * 8);
#pragma unroll
    for (int mt = 0; mt < 4; mt++)
#pragma unroll
      for (int nt = 0; nt < 2; nt++)
        acc[mt][nt] = __builtin_amdgcn_mfma_f32_16x16x32_bf16(af[mt], bf[nt], acc[mt][nt], 0, 0, 0);
  }
#pragma unroll
  for (int mt = 0; mt < 4; mt++)
#pragma unroll
    for (int nt = 0; nt < 2; nt++) {
      const int n = n0 + wv * 32 + nt * 16 + (lane & 15);
      const int mb = m0 + mt * 16 + ((lane >> 4) << 2);
#pragma unroll
      for (int r = 0; r < 4; r++) {
        if (n < 256)
          hWiF[(size_t)(mb + r) * 256 + n] = acc[mt][nt][r];
        else
          hWjB[(size_t)(mb + r) * 256 + (n - 256)] = f2b(acc[mt][nt][r]);
      }
    }
}

// ---------------------------------------------------------------------------
// Edge MLP + masked aggregation. (256,2): no spill (round-5 proven).
// ---------------------------------------------------------------------------
__global__ __launch_bounds__(256, 2) void k_edge(
    const float* __restrict__ hWiF, const u16* __restrict__ hWjB,
    const float* __restrict__ adj, const float* __restrict__ geb1,
    const u16* __restrict__ fragW2, const float* __restrict__ geb2,
    u16* __restrict__ aggB) {
  __shared__ __align__(16) u16 As[64 * 280];
  __shared__ float hi[256];
  __shared__ int jlist[256];
  __shared__ int cnt;
  const int t = threadIdx.x, lane = t & 63, wv = t >> 6;
  const int b = blockIdx.x >> 8, i = blockIdx.x & 255;
  if (t == 0) cnt = 0;
  __syncthreads();
  {
    const float a = adj[(size_t)(b * 256 + i) * 256 + t];
    hi[t] = hWiF[(size_t)(b * 256 + i) * 256 + t] + geb1[t];
    if (a != 0.f) { const int p = atomicAdd(&cnt, 1); jlist[p] = t; }
  }
  __syncthreads();
  const int nact = cnt;
  if (nact == 0) {
    if (lane < 16) {
#pragma unroll
      for (int nt = 0; nt < 4; nt++)
        aggB[(size_t)(b * 256 + i) * 256 + wv * 64 + nt * 16 + lane] = 0;
    }
    return;
  }
  const int nch = (nact + 63) >> 6;
  float bias2[4];
#pragma unroll
  for (int nt = 0; nt < 4; nt++) bias2[nt] = geb2[wv * 64 + nt * 16 + (lane & 15)];
  float aggAcc[4] = {0.f, 0.f, 0.f, 0.f};
  const u16* fw = fragW2 + lane * 8;

  for (int c = 0; c < nch; c++) {
    const int rows = min(64, nact - c * 64);
    {  // build A chunk: relu(bf16(hWj[j]) + hi) -> bf16
      const int r = t >> 2, q = t & 3;
      const bool valid = (r < rows);
      const int j = valid ? jlist[c * 64 + r] : jlist[0];
      const uint4* s4 = (const uint4*)(hWjB + (size_t)(b * 256 + j) * 256 + q * 64);
      u16* dstrow = As + r * 280 + q * 72;
#pragma unroll
      for (int ii = 0; ii < 8; ii++) {
        const uint4 v = s4[ii];
        const int k = q * 64 + ii * 8;
        float f0, f1, f2, f3, f4, f5, f6, f7;
        up2(v.x, f0, f1); up2(v.y, f2, f3); up2(v.z, f4, f5); up2(v.w, f6, f7);
        uint4 qd;
        qd.x = pkbf(fmaxf(f0 + hi[k + 0], 0.f), fmaxf(f1 + hi[k + 1], 0.f));
        qd.y = pkbf(fmaxf(f2 + hi[k + 2], 0.f), fmaxf(f3 + hi[k + 3], 0.f));
        qd.z = pkbf(fmaxf(f4 + hi[k + 4], 0.f), fmaxf(f5 + hi[k + 5], 0.f));
        qd.w = pkbf(fmaxf(f6 + hi[k + 6], 0.f), fmaxf(f7 + hi[k + 7], 0.f));
        *(uint4*)(dstrow + ii * 8) = qd;
      }
    }
    __syncthreads();
    f4v acc[4][4];
#pragma unroll
    for (int jt = 0; jt < 4; jt++)
#pragma unroll
      for (int nt = 0; nt < 4; nt++) acc[jt][nt] = (f4v){0.f, 0.f, 0.f, 0.f};
    bf8v bcur[4];
#pragma unroll
    for (int nt = 0; nt < 4; nt++)
      bcur[nt] = *(const bf8v*)(fw + (size_t)((wv * 4 + nt) * 8 + 0) * 512);
#pragma unroll
    for (int kt = 0; kt < 8; kt++) {
      bf8v bnxt[4];
      if (kt < 7) {
#pragma unroll
        for (int nt = 0; nt < 4; nt++)
          bnxt[nt] = *(const bf8v*)(fw + (size_t)((wv * 4 + nt) * 8 + kt + 1) * 512);
      }
      bf8v af[4];
      const int coff = (kt >> 1) * 72 + (kt & 1) * 32 + ((lane >> 4) << 3);
#pragma unroll
      for (int jt = 0; jt < 4; jt++)
        af[jt] = *(const bf8v*)(As + (jt * 16 + (lane & 15)) * 280 + coff);
#pragma unroll
      for (int nt = 0; nt < 4; nt++)
#pragma unroll
        for (int jt = 0; jt < 4; jt++)
          acc[jt][nt] = __builtin_amdgcn_mfma_f32_16x16x32_bf16(af[jt], bcur[nt], acc[jt][nt], 0, 0, 0);
      if (kt < 7) {
#pragma unroll
        for (int nt = 0; nt < 4; nt++) bcur[nt] = bnxt[nt];
      }
    }
    const int rbase = (lane >> 4) * 4;
#pragma unroll
    for (int nt = 0; nt < 4; nt++) {
      float s = 0.f;
#pragma unroll
      for (int jt = 0; jt < 4; jt++) {
        const int r0 = jt * 16 + rbase;
#pragma unroll
        for (int r = 0; r < 4; r++) {
          const float e = fmaxf(acc[jt][nt][r] + bias2[nt], 0.f);
          s += (r0 + r < rows) ? e : 0.f;
        }
      }
      s += __shfl_xor(s, 16);
      s += __shfl_xor(s, 32);
      aggAcc[nt] += s;
    }
    __syncthreads();
  }
  if (lane < 16) {
#pragma unroll
    for (int nt = 0; nt < 4; nt++) {
      const int n = wv * 64 + nt * 16 + lane;
      aggB[(size_t)(b * 256 + i) * 256 + n] = f2b(aggAcc[nt]);
    }
  }
}

// ---------------------------------------------------------------------------
// Merged tail: 64 blocks x 1024 threads, 4 per-batch pipelines of 16 blocks.
// Phase 3 now runs on FOUR blocks per batch (m<4) with round-5-verified
// global-intermediate helpers + 7 radius-4 batch-local barriers: round-10
// proved phase 3 (35us) is per-CU fetch-throughput-bound (L2 prefetch was
// null) -> spread the 1.38MB fragment stream over 4 CUs.
// ---------------------------------------------------------------------------
__device__ __forceinline__ void barArrive(int* c) {
  __syncthreads();
  if (threadIdx.x == 0)
    __hip_atomic_fetch_add(c, 1, __ATOMIC_RELEASE, __HIP_MEMORY_SCOPE_AGENT);
}
__device__ __forceinline__ void barWait(int* c, int target) {
  if (threadIdx.x == 0) {
    int it = 0;
    while (__hip_atomic_load(c, __ATOMIC_ACQUIRE, __HIP_MEMORY_SCOPE_AGENT) < target) {
      __builtin_amdgcn_s_sleep(8);
      if (((++it) & 255) == 0)
        __hip_atomic_fetch_add(c, 0, __ATOMIC_ACQ_REL, __HIP_MEMORY_SCOPE_AGENT);
    }
  }
  __syncthreads();
}
// phase-3 stage barrier: arrive + wait (monotone counter, target = 4*stage)
__device__ __forceinline__ void p3bar(int* c, int target) {
  __syncthreads();
  if (threadIdx.x == 0) {
    __hip_atomic_fetch_add(c, 1, __ATOMIC_RELEASE, __HIP_MEMORY_SCOPE_AGENT);
    int it = 0;
    while (__hip_atomic_load(c, __ATOMIC_ACQUIRE, __HIP_MEMORY_SCOPE_AGENT) < target) {
      __builtin_amdgcn_s_sleep(8);
      if (((++it) & 255) == 0)
        __hip_atomic_fetch_add(c, 0, __ATOMIC_ACQ_REL, __HIP_MEMORY_SCOPE_AGENT);
    }
  }
  __syncthreads();
}

// single-tile GEMM stage, 16 waves: wave w owns tile w; prefetched B-frag.
__device__ void g16w(const u16* Al, const u16* __restrict__ frag,
                     const float* bias, int relu, u16* Ol, int t) {
  const int lane = t & 63, w = t >> 6;  // [0,16)
  f4v acc = (f4v){0.f, 0.f, 0.f, 0.f};
  const u16* abase = Al + (lane & 15) * 264 + ((lane >> 4) << 3);
  const u16* fb = frag + ((size_t)(w * 8) * 64 + lane) * 8;
  bf8v bc = *(const bf8v*)fb;
#pragma unroll
  for (int kt = 0; kt < 8; kt++) {
    bf8v bn;
    if (kt < 7) bn = *(const bf8v*)(fb + (size_t)(kt + 1) * 512);
    const bf8v af = *(const bf8v*)(abase + kt * 32);
    acc = __builtin_amdgcn_mfma_f32_16x16x32_bf16(af, bc, acc, 0, 0, 0);
    if (kt < 7) bc = bn;
  }
  const int col = w * 16 + (lane & 15);
  const float bv = bias[col];
#pragma unroll
  for (int r = 0; r < 4; r++) {
    const int row = ((lane >> 4) << 2) + r;
    float v = acc[r] + bv;
    if (relu) v = fmaxf(v, 0.f);
    Ol[row * 264 + col] = f2b(v);
  }
}

// KV stage, 16 waves x 2 tiles: wave w owns tiles {2w, 2w+1} (512 cols).
__device__ void g16kv2(const u16* Al, const u16* __restrict__ frag,
                       const float* bias, u16* outG, int t) {
  const int lane = t & 63, w = t >> 6;
  f4v acc[2];
  acc[0] = (f4v){0.f, 0.f, 0.f, 0.f};
  acc[1] = (f4v){0.f, 0.f, 0.f, 0.f};
  const u16* abase = Al + (lane & 15) * 264 + ((lane >> 4) << 3);
  const u16* f0 = frag + ((size_t)((w * 2 + 0) * 8) * 64 + lane) * 8;
  const u16* f1 = frag + ((size_t)((w * 2 + 1) * 8) * 64 + lane) * 8;
  bf8v bc0 = *(const bf8v*)f0;
  bf8v bc1 = *(const bf8v*)f1;
#pragma unroll
  for (int kt = 0; kt < 8; kt++) {
    bf8v bn0, bn1;
    if (kt < 7) {
      bn0 = *(const bf8v*)(f0 + (size_t)(kt + 1) * 512);
      bn1 = *(const bf8v*)(f1 + (size_t)(kt + 1) * 512);
    }
    const bf8v af = *(const bf8v*)(abase + kt * 32);
    acc[0] = __builtin_amdgcn_mfma_f32_16x16x32_bf16(af, bc0, acc[0], 0, 0, 0);
    acc[1] = __builtin_amdgcn_mfma_f32_16x16x32_bf16(af, bc1, acc[1], 0, 0, 0);
    if (kt < 7) { bc0 = bn0; bc1 = bn1; }
  }
#pragma unroll
  for (int nt = 0; nt < 2; nt++) {
    const int col = (w * 2 + nt) * 16 + (lane & 15);
    const float bv = bias[col];
#pragma unroll
    for (int r = 0; r < 4; r++) {
      const int row = ((lane >> 4) << 2) + r;
      outG[(size_t)row * 512 + col] = f2b(acc[nt][r] + bv);
    }
  }
}

// MAB1 attention, 8-row half; per-row arithmetic order identical to original.
__device__ void attn_half(const u16* __restrict__ qbuf,
                          const u16* __restrict__ kbuf, const u16* __restrict__ vbuf,
                          float* __restrict__ oF, u16* __restrict__ oB,
                          int b, int hd, int half, float* qs, float* sc, float* vs, int t) {
  const int lane = t & 63, w = t >> 6;
  const int Lk = 256;
  if (t < 64) {
    const int row = t >> 2, part = t & 3;
    const uint4 q4 = *(const uint4*)(qbuf + (size_t)row * 256 + hd * 32 + part * 8);
    float f0, f1, f2, f3, f4, f5, f6, f7;
    up2(q4.x, f0, f1); up2(q4.y, f2, f3); up2(q4.z, f4, f5); up2(q4.w, f6, f7);
    float4* d = (float4*)(qs + row * 32 + part * 8);
    d[0] = make_float4(f0, f1, f2, f3);
    d[1] = make_float4(f4, f5, f6, f7);
  }
  __syncthreads();
  if (t < 256) {
    float kv[32];
    const uint4* kp = (const uint4*)(kbuf + (size_t)(b * Lk + t) * 512 + hd * 32);
#pragma unroll
    for (int c4 = 0; c4 < 4; c4++) {
      const uint4 k4 = kp[c4];
      up2(k4.x, kv[c4 * 8 + 0], kv[c4 * 8 + 1]);
      up2(k4.y, kv[c4 * 8 + 2], kv[c4 * 8 + 3]);
      up2(k4.z, kv[c4 * 8 + 4], kv[c4 * 8 + 5]);
      up2(k4.w, kv[c4 * 8 + 6], kv[c4 * 8 + 7]);
    }
    for (int r = 0; r < 8; r++) {
      const int grow = half * 8 + r;
      float s = 0.f;
#pragma unroll
      for (int d = 0; d < 32; d++) s += qs[grow * 32 + d] * kv[d];
      sc[r * 256 + t] = s * 0.0625f;
    }
  }
  __syncthreads();
  if (w < 8) {
    const int r = w;
    float v[4];
    float mx = -1e30f;
#pragma unroll
    for (int q2 = 0; q2 < 4; q2++) {
      v[q2] = sc[r * 256 + lane + q2 * 64];
      mx = fmaxf(mx, v[q2]);
    }
    for (int off = 32; off; off >>= 1) mx = fmaxf(mx, __shfl_xor(mx, off));
    float sum = 0.f;
#pragma unroll
    for (int q2 = 0; q2 < 4; q2++) { v[q2] = __expf(v[q2] - mx); sum += v[q2]; }
    for (int off = 32; off; off >>= 1) sum += __shfl_xor(sum, off);
    const float inv = 1.f / sum;
#pragma unroll
    for (int q2 = 0; q2 < 4; q2++) sc[r * 256 + lane + q2 * 64] = v[q2] * inv;
  }
  __syncthreads();
  {
    const int row = t >> 2, part = t & 3;
    const uint4 v4 = *(const uint4*)(vbuf + (size_t)(b * Lk + row) * 512 + hd * 32 + part * 8);
    float f0, f1, f2, f3, f4, f5, f6, f7;
    up2(v4.x, f0, f1); up2(v4.y, f2, f3); up2(v4.z, f4, f5); up2(v4.w, f6, f7);
    float4* d = (float4*)(vs + row * 32 + part * 8);
    d[0] = make_float4(f0, f1, f2, f3);
    d[1] = make_float4(f4, f5, f6, f7);
  }
  __syncthreads();
  if (t < 256) {
    const int r0 = t >> 5, d = t & 31;
    const int grow = half * 8 + r0;
    float a0 = qs[grow * 32 + d];
#pragma unroll 4
    for (int j = 0; j < Lk; j++) a0 += sc[r0 * 256 + j] * vs[j * 32 + d];
    const int c0 = hd * 32 + d;
    oF[(size_t)(b * 16 + grow) * 256 + c0] = a0;
    oB[(size_t)(b * 16 + grow) * 256 + c0] = f2b(a0);
  }
}

// ---- round-5 VERIFIED global-addressed single-tile helpers ----
__device__ void wprojG_g(const u16* __restrict__ o1b, const float* __restrict__ o1f,
                         const u16* __restrict__ frag, const float* __restrict__ bias,
                         u16* act, float* resid, int b, int T, int lane) {
  f4v acc = (f4v){0.f, 0.f, 0.f, 0.f};
  const u16* abase = o1b + (size_t)(b * 16 + (lane & 15)) * 256 + ((lane >> 4) << 3);
  const u16* fbase = frag + ((size_t)(T * 8) * 64 + lane) * 8;
#pragma unroll
  for (int kt = 0; kt < 8; kt++)
    acc = __builtin_amdgcn_mfma_f32_16x16x32_bf16(*(const bf8v*)(abase + kt * 32),
                                                  *(const bf8v*)(fbase + (size_t)kt * 512), acc, 0, 0, 0);
  const int col = T * 16 + (lane & 15);
  const float bv = bias[col];
#pragma unroll
  for (int r = 0; r < 4; r++) {
    const int row = ((lane >> 4) << 2) + r;
    const float v = fmaxf(acc[r] + bv, 0.f) + o1f[(size_t)(b * 16 + row) * 256 + col];
    resid[(size_t)(b * 16 + row) * 256 + col] = v;
    act[(size_t)(b * 16 + row) * 256 + col] = f2b(v);
  }
}

__device__ void wprojQ_g(const u16* __restrict__ act, const u16* __restrict__ frag,
                         const float* __restrict__ bias, u16* qkv, int b, int T, int lane) {
  f4v acc = (f4v){0.f, 0.f, 0.f, 0.f};
  const u16* abase = act + (size_t)(b * 16 + (lane & 15)) * 256 + ((lane >> 4) << 3);
  const u16* fbase = frag + ((size_t)(T * 8) * 64 + lane) * 8;
#pragma unroll
  for (int kt = 0; kt < 8; kt++)
    acc = __builtin_amdgcn_mfma_f32_16x16x32_bf16(*(const bf8v*)(abase + kt * 32),
                                                  *(const bf8v*)(fbase + (size_t)kt * 512), acc, 0, 0, 0);
  const int col = T * 16 + (lane & 15);
  const float bv = bias[col];
#pragma unroll
  for (int r = 0; r < 4; r++) {
    const int row = ((lane >> 4) << 2) + r;
    qkv[(size_t)(b * 16 + row) * 768 + col] = f2b(acc[r] + bv);
  }
}

__device__ void wprojR_g(const u16* __restrict__ actIn, const u16* __restrict__ frag,
                         const float* __restrict__ bias, u16* actOut, float* resid,
                         int b, int T, int lane) {
  f4v acc = (f4v){0.f, 0.f, 0.f, 0.f};
  const u16* abase = actIn + (size_t)(b * 16 + (lane & 15)) * 256 + ((lane >> 4) << 3);
  const u16* fbase = frag + ((size_t)(T * 8) * 64 + lane) * 8;
#pragma unroll
  for (int kt = 0; kt < 8; kt++)
    acc = __builtin_amdgcn_mfma_f32_16x16x32_bf16(*(const bf8v*)(abase + kt * 32),
                                                  *(const bf8v*)(fbase + (size_t)kt * 512), acc, 0, 0, 0);
  const int col = T * 16 + (lane & 15);
  const float bv = bias[col];
#pragma unroll
  for (int r = 0; r < 4; r++) {
    const int row = ((lane >> 4) << 2) + r;
    const float v = fmaxf(acc[r] + bv, 0.f) + resid[(size_t)(b * 16 + row) * 256 + col];
    resid[(size_t)(b * 16 + row) * 256 + col] = v;
    actOut[(size_t)(b * 16 + row) * 256 + col] = f2b(v);
  }
}

__device__ void wprojF_g(const u16* __restrict__ act, const u16* __restrict__ frag,
                         const float* __restrict__ bias, float* __restrict__ outF,
                         int b, int T, int lane) {
  f4v acc = (f4v){0.f, 0.f, 0.f, 0.f};
  const u16* abase = act + (size_t)(b * 16 + (lane & 15)) * 256 + ((lane >> 4) << 3);
  const u16* fbase = frag + ((size_t)(T * 8) * 64 + lane) * 8;
#pragma unroll
  for (int kt = 0; kt < 8; kt++)
    acc = __builtin_amdgcn_mfma_f32_16x16x32_bf16(*(const bf8v*)(abase + kt * 32),
                                                  *(const bf8v*)(fbase + (size_t)kt * 512), acc, 0, 0, 0);
  const int col = T * 16 + (lane & 15);
  const float bv = bias[col];
#pragma unroll
  for (int r = 0; r < 4; r++) {
    const int row = ((lane >> 4) << 2) + r;
    outF[(size_t)(b * 16 + row) * 384 + col] = acc[r] + bv;
  }
}

__device__ void attnB_g(const u16* __restrict__ qkv, float* resid, u16* actOut,
                        float* ps, int b, int hd, int lane) {
  const int r = lane & 15, cg = lane >> 4;
  float qv[32];
  {
    const uint4* qp = (const uint4*)(qkv + (size_t)(b * 16 + r) * 768 + hd * 32);
#pragma unroll
    for (int c4 = 0; c4 < 4; c4++) {
      const uint4 q4 = qp[c4];
      up2(q4.x, qv[c4 * 8 + 0], qv[c4 * 8 + 1]);
      up2(q4.y, qv[c4 * 8 + 2], qv[c4 * 8 + 3]);
      up2(q4.z, qv[c4 * 8 + 4], qv[c4 * 8 + 5]);
      up2(q4.w, qv[c4 * 8 + 6], qv[c4 * 8 + 7]);
    }
  }
  float p[4];
#pragma unroll
  for (int c = 0; c < 4; c++) {
    const int cc = cg * 4 + c;
    const uint4* kp = (const uint4*)(qkv + (size_t)(b * 16 + cc) * 768 + 256 + hd * 32);
    float s = 0.f;
#pragma unroll
    for (int c4 = 0; c4 < 4; c4++) {
      const uint4 k4 = kp[c4];
      float k0, k1;
      up2(k4.x, k0, k1); s += qv[c4 * 8 + 0] * k0 + qv[c4 * 8 + 1] * k1;
      up2(k4.y, k0, k1); s += qv[c4 * 8 + 2] * k0 + qv[c4 * 8 + 3] * k1;
      up2(k4.z, k0, k1); s += qv[c4 * 8 + 4] * k0 + qv[c4 * 8 + 5] * k1;
      up2(k4.w, k0, k1); s += qv[c4 * 8 + 6] * k0 + qv[c4 * 8 + 7] * k1;
    }
    p[c] = s * 0.0625f;
  }
  float mx = fmaxf(fmaxf(p[0], p[1]), fmaxf(p[2], p[3]));
  mx = fmaxf(mx, __shfl_xor(mx, 16));
  mx = fmaxf(mx, __shfl_xor(mx, 32));
  float sum = 0.f;
#pragma unroll
  for (int c = 0; c < 4; c++) { p[c] = __expf(p[c] - mx); sum += p[c]; }
  sum += __shfl_xor(sum, 16);
  sum += __shfl_xor(sum, 32);
  const float inv = 1.f / sum;
#pragma unroll
  for (int c = 0; c < 4; c++) ps[r * 16 + cg * 4 + c] = p[c] * inv;
  float o[8];
#pragma unroll
  for (int j = 0; j < 8; j++) o[j] = qv[cg * 8 + j];
#pragma unroll
  for (int c = 0; c < 16; c++) {
    const float pv = ps[r * 16 + c];
    const uint4 v4 = *(const uint4*)(qkv + (size_t)(b * 16 + c) * 768 + 512 + hd * 32 + cg * 8);
    float v0, v1;
    up2(v4.x, v0, v1); o[0] += pv * v0; o[1] += pv * v1;
    up2(v4.y, v0, v1); o[2] += pv * v0; o[3] += pv * v1;
    up2(v4.z, v0, v1); o[4] += pv * v0; o[5] += pv * v1;
    up2(v4.w, v0, v1); o[6] += pv * v0; o[7] += pv * v1;
  }
  const int col0 = hd * 32 + cg * 8;
#pragma unroll
  for (int j = 0; j < 8; j++) resid[(size_t)(b * 16 + r) * 256 + col0 + j] = o[j];
  unsigned* ob = (unsigned*)(actOut + (size_t)(b * 16 + r) * 256 + col0);
  ob[0] = pkbf(o[0], o[1]); ob[1] = pkbf(o[2], o[3]);
  ob[2] = pkbf(o[4], o[5]); ob[3] = pkbf(o[6], o[7]);
}

struct TailArgs {
  const u16 *agg, *fGn1, *fGn2, *fGo, *fKV0, *fQKV1, *fQKV2, *fO0, *fO1, *fO2, *fFin, *q1b;
  const float *gnb1, *gnb2, *gob, *bkv0, *bqkv1, *bqkv2, *mbo, *finb;
  u16 *kv1, *o1b;
  float *o1f, *outF;
  u16 *act0, *act1, *qkv;
  float* resid;
  int* bar;
};

// Merged tail kernel: 4 per-batch pipelines x 16 blocks.
__global__ __launch_bounds__(1024) void k_tailM(TailArgs a) {
  __shared__ __align__(16) char smem[58368];
  const int bid = blockIdx.x, t = threadIdx.x;
  const int lane = t & 63, w = t >> 6;
  const int g = bid >> 4, m = bid & 15;
  int* c1 = a.bar + g * 64;       // phase1-done counter (own 64B line)
  int* c2 = a.bar + g * 64 + 16;  // phase2-done counter
  int* c3 = a.bar + g * 64 + 32;  // phase3 stage counter (monotone)

  {  // ---- phase 1: node MLP + KV0 (16 rows per block) ----
    u16* actA = (u16*)smem;
    u16* actB = (u16*)(smem + 8448);
    const int r0 = bid * 16;
    if (t < 512) {
      const int row = t >> 5, ch = t & 31;
      *(uint4*)(actA + row * 264 + ch * 8) =
          *(const uint4*)(a.agg + (size_t)(r0 + row) * 256 + ch * 8);
    }
    __syncthreads();
    g16w(actA, a.fGn1, a.gnb1, 1, actB, t); __syncthreads();
    g16w(actB, a.fGn2, a.gnb2, 1, actA, t); __syncthreads();
    g16w(actA, a.fGo, a.gob, 0, actB, t); __syncthreads();
    g16kv2(actB, a.fKV0, a.bkv0, a.kv1 + (size_t)r0 * 512, t);
  }
  barArrive(c1);
  barWait(c1, 16);
  {  // ---- phase 2: MAB1 attention, head m&7, half m>>3 ----
    float* qs = (float*)smem;
    float* sc = (float*)(smem + 2048);
    float* vs = (float*)(smem + 18432);
    attn_half(a.q1b, a.kv1, a.kv1 + 256, a.o1f, a.o1b,
              g, m & 7, m >> 3, qs, sc, vs, t);
  }
  barArrive(c2);
  if (m >= 4) return;
  barWait(c2, 16);
  {  // ---- phase 3: MAB2+MAB3+final, 4 blocks per batch, 7 radius-4 bars ----
    const int b = g;
    float* psW = (float*)smem + w * 256;  // w<2 only
    if (w < 4)  wprojG_g(a.o1b, a.o1f, a.fO0, a.mbo, a.act0, a.resid, b, m * 4 + w, lane);
    p3bar(c3, 4 * 1);
    if (w < 12) wprojQ_g(a.act0, a.fQKV1, a.bqkv1, a.qkv, b, m * 12 + w, lane);
    p3bar(c3, 4 * 2);
    if (w < 2)  attnB_g(a.qkv, a.resid, a.act1, psW, b, m * 2 + w, lane);
    p3bar(c3, 4 * 3);
    if (w < 4)  wprojR_g(a.act1, a.fO1, a.mbo + 256, a.act0, a.resid, b, m * 4 + w, lane);
    p3bar(c3, 4 * 4);
    if (w < 12) wprojQ_g(a.act0, a.fQKV2, a.bqkv2, a.qkv, b, m * 12 + w, lane);
    p3bar(c3, 4 * 5);
    if (w < 2)  attnB_g(a.qkv, a.resid, a.act1, psW, b, m * 2 + w, lane);
    p3bar(c3, 4 * 6);
    if (w < 4)  wprojR_g(a.act1, a.fO2, a.mbo + 512, a.act0, a.resid, b, m * 4 + w, lane);
    p3bar(c3, 4 * 7);
    if (w < 6)  wprojF_g(a.act0, a.fFin, a.finb, a.outF, b, m * 6 + w, lane);
  }
}

// ---------------------------------------------------------------------------
extern "C" void kernel_launch(void* const* d_in, const int* in_sizes, int n_in,
                              void* d_out, int out_size, void* d_ws, size_t ws_size,
                              hipStream_t stream) {
  const float* x    = (const float*)d_in[0];
  const float* adj  = (const float*)d_in[1];
  const float* ginW = (const float*)d_in[2];
  const float* ginb = (const float*)d_in[3];
  const float* geW1 = (const float*)d_in[4];
  const float* geb1 = (const float*)d_in[5];
  const float* geW2 = (const float*)d_in[6];
  const float* geb2 = (const float*)d_in[7];
  const float* gnW1 = (const float*)d_in[8];
  const float* gnb1 = (const float*)d_in[9];
  const float* gnW2 = (const float*)d_in[10];
  const float* gnb2 = (const float*)d_in[11];
  const float* goW  = (const float*)d_in[12];
  const float* gob  = (const float*)d_in[13];
  const float* S    = (const float*)d_in[14];
  const float* mWq  = (const float*)d_in[15];
  const float* mbq  = (const float*)d_in[16];
  const float* mWk  = (const float*)d_in[17];
  const float* mbk  = (const float*)d_in[18];
  const float* mWv  = (const float*)d_in[19];
  const float* mbv  = (const float*)d_in[20];
  const float* mWo  = (const float*)d_in[21];
  const float* mbo  = (const float*)d_in[22];
  const float* finW = (const float*)d_in[23];
  const float* finb = (const float*)d_in[24];
  (void)in_sizes; (void)n_in; (void)out_size; (void)ws_size;

  char* wp = (char*)d_ws;
  size_t off = 0;
  auto alloc = [&](size_t bytes) -> char* {
    char* p = wp + off;
    off += (bytes + 255) & ~(size_t)255;
    return p;
  };
  u16* h_bf     = (u16*)alloc(1024 * 256 * 2);
  float* hWiF   = (float*)alloc((size_t)1024 * 256 * 4);
  u16* hWjB     = (u16*)alloc(1024 * 256 * 2);
  u16* fWiWj    = (u16*)alloc(512 * 256 * 2);
  u16* fW2      = (u16*)alloc(256 * 256 * 2);
  u16* fGn1     = (u16*)alloc(256 * 256 * 2);
  u16* fGn2     = (u16*)alloc(256 * 256 * 2);
  u16* fGo      = (u16*)alloc(256 * 256 * 2);
  u16* fKV0     = (u16*)alloc(512 * 256 * 2);
  u16* fQKV1    = (u16*)alloc(768 * 256 * 2);
  u16* fQKV2    = (u16*)alloc(768 * 256 * 2);
  u16* fO0      = (u16*)alloc(256 * 256 * 2);
  u16* fO1      = (u16*)alloc(256 * 256 * 2);
  u16* fO2      = (u16*)alloc(256 * 256 * 2);
  u16* fFin     = (u16*)alloc(384 * 256 * 2);
  float* bkv0   = (float*)alloc(512 * 4);
  float* bqkv1  = (float*)alloc(768 * 4);
  float* bqkv2  = (float*)alloc(768 * 4);
  u16* q1b      = (u16*)alloc(16 * 256 * 2);
  u16* agg_b    = (u16*)alloc(1024 * 256 * 2);
  u16* kv1      = (u16*)alloc(1024 * 512 * 2);
  float* o1f    = (float*)alloc(64 * 256 * 4);
  u16* o1b      = (u16*)alloc(64 * 256 * 2);
  u16* act0_g   = (u16*)alloc(64 * 256 * 2);
  u16* act1_g   = (u16*)alloc(64 * 256 * 2);
  u16* qkv_g    = (u16*)alloc(64 * 768 * 2);
  float* resid_g= (float*)alloc(64 * 256 * 4);
  int* bar      = (int*)alloc(1024);

  PreArgs P{};
  int nj = 0, tiles = 0;
  auto addF = [&](const float* s, int stride, u16* d, int nT) {
    P.fsrc[nj] = s; P.fdst[nj] = d; P.fstride[nj] = stride; P.fbase[nj] = tiles;
    tiles += nT; nj++;
  };
  addF(geW1, 256, fWiWj, 16);
  addF(geW1 + 65536, 256, fWiWj + 16 * 4096, 16);
  addF(geW2, 256, fW2, 16);
  addF(gnW1, 256, fGn1, 16);
  addF(gnW2, 256, fGn2, 16);
  addF(goW, 256, fGo, 16);
  addF(mWk, 256, fKV0, 16);
  addF(mWv, 256, fKV0 + 16 * 4096, 16);
  addF(mWq + 65536, 256, fQKV1, 16);
  addF(mWk + 65536, 256, fQKV1 + 16 * 4096, 16);
  addF(mWv + 65536, 256, fQKV1 + 32 * 4096, 16);
  addF(mWq + 131072, 256, fQKV2, 16);
  addF(mWk + 131072, 256, fQKV2 + 16 * 4096, 16);
  addF(mWv + 131072, 256, fQKV2 + 32 * 4096, 16);
  addF(mWo, 256, fO0, 16);
  addF(mWo + 65536, 256, fO1, 16);
  addF(mWo + 131072, 256, fO2, 16);
  addF(finW, 384, fFin, 24);
  P.fbase[nj] = tiles;
  P.fragTiles = tiles;        // 296
  P.hBase = tiles;
  P.prepBid = tiles + 256;    // 552
  P.q1Bid = tiles + 257;      // 553
  P.x = x; P.ginW = ginW; P.ginb = ginb; P.h_bf = h_bf;
  P.mbk = mbk; P.mbv = mbv; P.mbq = mbq; P.S = S; P.mWq = mWq;
  P.bkv0 = bkv0; P.bqkv1 = bqkv1; P.bqkv2 = bqkv2; P.q1b = q1b;
  P.bar = bar;

  TailArgs T{};
  T.agg = agg_b; T.fGn1 = fGn1; T.fGn2 = fGn2; T.fGo = fGo; T.fKV0 = fKV0;
  T.fQKV1 = fQKV1; T.fQKV2 = fQKV2; T.fO0 = fO0; T.fO1 = fO1; T.fO2 = fO2;
  T.fFin = fFin; T.q1b = q1b;
  T.gnb1 = gnb1; T.gnb2 = gnb2; T.gob = gob;
  T.bkv0 = bkv0; T.bqkv1 = bqkv1; T.bqkv2 = bqkv2; T.mbo = mbo; T.finb = finb;
  T.kv1 = kv1; T.o1b = o1b; T.o1f = o1f; T.outF = (float*)d_out;
  T.act0 = act0_g; T.act1 = act1_g; T.qkv = qkv_g; T.resid = resid_g;
  T.bar = bar;

  k_pre<<<dim3(tiles + 258), dim3(256), 0, stream>>>(P);
  k_wiwj<<<dim3(16, 4), dim3(256), 0, stream>>>(h_bf, fWiWj, hWiF, hWjB);
  k_edge<<<dim3(1024), dim3(256), 0, stream>>>(hWiF, hWjB, adj, geb1, fW2, geb2, agg_b);
  k_tailM<<<dim3(64), dim3(1024), 0, stream>>>(T);
}